// Round 1
// baseline (322.420 us; speedup 1.0000x reference)
//
#include <hip/hip_runtime.h>

using bf16   = __bf16;
using bf16x4 = __bf16 __attribute__((ext_vector_type(4)));
using bf16x8 = __bf16 __attribute__((ext_vector_type(8)));
using f32x4  = float __attribute__((ext_vector_type(4)));
using u32x2  = unsigned int __attribute__((ext_vector_type(2)));
using u32x4  = unsigned int __attribute__((ext_vector_type(4)));

#define L_SEQ  2048
#define DMODEL 2048
#define NQH    32
#define NKVH   8
#define HDIM   64
#define QKV_N  3072   // NQH*HDIM + 2*NKVH*HDIM

// ---------- helpers ----------
__device__ __forceinline__ bf16x8 lds_ld8(const bf16* p) {
  // 8-byte-aligned 16B load as two u32x2 (LDS rows have pitch 68 elems = 136 B,
  // so 16B-aligned b128 is not guaranteed; b64 pairs are conflict-friendly here)
  u32x2 a = *reinterpret_cast<const u32x2*>(p);
  u32x2 b = *reinterpret_cast<const u32x2*>(p + 4);
  u32x4 u = {a.x, a.y, b.x, b.y};
  return __builtin_bit_cast(bf16x8, u);
}

__device__ __forceinline__ void gload_lds16(const void* g, void* lds) {
  __builtin_amdgcn_global_load_lds((__attribute__((address_space(1))) void*)(g),
                                   (__attribute__((address_space(3))) void*)(lds),
                                   16, 0, 0);
}

// ---------- fp32 -> bf16 convert ----------
__global__ void cvt_f32_bf16(const float* __restrict__ in, bf16* __restrict__ out, long n) {
  const long stride = (long)gridDim.x * blockDim.x;
  const long n4 = n >> 2;
  for (long i = (long)blockIdx.x * blockDim.x + threadIdx.x; i < n4; i += stride) {
    const float4 v = reinterpret_cast<const float4*>(in)[i];
    bf16x4 o = { (bf16)v.x, (bf16)v.y, (bf16)v.z, (bf16)v.w };
    reinterpret_cast<bf16x4*>(out)[i] = o;
  }
}

// ---------- bf16 GEMM: C(MxN) = A(MxK) * B(NxK)^T, 128x128 tile, BK=64 ----------
// global_load_lds(16B) staging with XOR-swizzled global source (linear LDS dest),
// swizzled ds_read_b128 fragment loads -> 2-way (free) bank aliasing.
template <typename OutT>
__global__ __launch_bounds__(256)
void gemm_bt(const bf16* __restrict__ A, const bf16* __restrict__ B,
             OutT* __restrict__ C, int M, int N, int K) {
  __shared__ bf16 As[128 * 64];
  __shared__ bf16 Bs[128 * 64];
  const int tid = threadIdx.x;
  const int w = tid >> 6, l = tid & 63;
  const int wr = w >> 1, wc = w & 1;
  const int lq = l & 15, lg = l >> 4;
  const long m0 = (long)blockIdx.y * 128;
  const long n0 = (long)blockIdx.x * 128;

  // staging geometry: lane covers (row = base + l/8, 16B-block = l%8)
  const int lrow = l >> 3;
  const int scol = ((l & 7) ^ lrow) << 3;   // swizzled element column within BK

  f32x4 acc[4][4];
#pragma unroll
  for (int i = 0; i < 4; ++i)
#pragma unroll
    for (int j = 0; j < 4; ++j) acc[i][j] = f32x4{0.f, 0.f, 0.f, 0.f};

  for (int k0 = 0; k0 < K; k0 += 64) {
#pragma unroll
    for (int i = 0; i < 4; ++i) {
      const int r0 = (w * 4 + i) * 8;
      gload_lds16(A + (m0 + r0 + lrow) * (long)K + k0 + scol, &As[r0 * 64]);
      gload_lds16(B + (n0 + r0 + lrow) * (long)K + k0 + scol, &Bs[r0 * 64]);
    }
    __syncthreads();
#pragma unroll
    for (int kk = 0; kk < 2; ++kk) {
      bf16x8 af[4], bfr[4];
#pragma unroll
      for (int t = 0; t < 4; ++t) {
        const int rowA = wr * 64 + t * 16 + lq;
        const int blkA = (kk * 4 + lg) ^ (rowA & 7);
        af[t] = *reinterpret_cast<const bf16x8*>(&As[rowA * 64 + blkA * 8]);
        const int rowB = wc * 64 + t * 16 + lq;
        const int blkB = (kk * 4 + lg) ^ (rowB & 7);
        bfr[t] = *reinterpret_cast<const bf16x8*>(&Bs[rowB * 64 + blkB * 8]);
      }
#pragma unroll
      for (int mt = 0; mt < 4; ++mt)
#pragma unroll
        for (int nt = 0; nt < 4; ++nt)
          acc[mt][nt] = __builtin_amdgcn_mfma_f32_16x16x32_bf16(af[mt], bfr[nt], acc[mt][nt], 0, 0, 0);
    }
    __syncthreads();
  }

#pragma unroll
  for (int mt = 0; mt < 4; ++mt)
#pragma unroll
    for (int r = 0; r < 4; ++r) {
      const long row = m0 + wr * 64 + mt * 16 + lg * 4 + r;
#pragma unroll
      for (int nt = 0; nt < 4; ++nt) {
        const long col = n0 + wc * 64 + nt * 16 + lq;
        C[row * (long)N + col] = (OutT)acc[mt][nt][r];
      }
    }
}

// ---------- RoPE + RMSNorm for Q and K (one wave per (pos, head) row) ----------
// Q additionally scaled by SCALE=0.125 (exact power of 2, folded into bf16 Q).
__global__ __launch_bounds__(256)
void rope_rms(const bf16* __restrict__ qkv, const float* __restrict__ qg,
              const float* __restrict__ kg, bf16* __restrict__ qo, bf16* __restrict__ ko) {
  const int gid = blockIdx.x * 4 + (threadIdx.x >> 6);
  const int lane = threadIdx.x & 63;
  const int pos = gid / 40;
  const int hh = gid % 40;            // 0..31 q heads, 32..39 k heads
  const bool isq = hh < 32;
  const int col = isq ? hh * HDIM : NQH * HDIM + (hh - 32) * HDIM;

  float x = (float)qkv[(long)pos * QKV_N + col + lane];
  float p = __shfl_xor(x, 1);
  const float fi = (float)(lane & ~1) * (1.0f / 64.0f);
  const float inv = powf(50000.0f, -fi);
  const float ang = (float)pos * inv;
  const float sn = sinf(ang), cs = cosf(ang);
  // even lane: x1=x, x2=p -> x*c - p*s ; odd lane: x1=p, x2=x -> p*s + x*c
  const float r = (lane & 1) ? (p * sn + x * cs) : (x * cs - p * sn);

  float ss = r * r;
#pragma unroll
  for (int off = 1; off < 64; off <<= 1) ss += __shfl_xor(ss, off);
  const float scl = rsqrtf(ss * (1.0f / 64.0f) + 1e-5f);
  const float g = isq ? qg[lane] : kg[lane];
  const float o = r * scl * g;

  if (isq) qo[(long)pos * DMODEL + hh * HDIM + lane] = (bf16)(o * 0.125f);
  else     ko[(long)pos * (NKVH * HDIM) + (hh - 32) * HDIM + lane] = (bf16)o;
}

// ---------- V transpose: qkv cols [2560,3072) -> vt[h][d][l] ----------
__global__ __launch_bounds__(256)
void vtrans(const bf16* __restrict__ qkv, bf16* __restrict__ vt) {
  __shared__ bf16 t[64][72];
  const int hh = blockIdx.x >> 5;
  const int l0 = (blockIdx.x & 31) * 64;
  const int r = threadIdx.x >> 2;            // 0..63
  const int c = (threadIdx.x & 3) * 16;      // 0,16,32,48

  const bf16* g = qkv + (long)(l0 + r) * QKV_N + (NQH * HDIM + NKVH * HDIM) + hh * HDIM + c;
  u32x4 u0 = reinterpret_cast<const u32x4*>(g)[0];
  u32x4 u1 = reinterpret_cast<const u32x4*>(g)[1];
  bf16* dst = &t[r][c];
  reinterpret_cast<u32x2*>(dst)[0] = u32x2{u0.x, u0.y};
  reinterpret_cast<u32x2*>(dst)[1] = u32x2{u0.z, u0.w};
  reinterpret_cast<u32x2*>(dst)[2] = u32x2{u1.x, u1.y};
  reinterpret_cast<u32x2*>(dst)[3] = u32x2{u1.z, u1.w};
  __syncthreads();

  union { bf16 b[8]; u32x4 u; } o0, o1;
#pragma unroll
  for (int j = 0; j < 8; ++j) { o0.b[j] = t[c + j][r]; o1.b[j] = t[c + 8 + j][r]; }
  bf16* od = vt + ((long)hh * HDIM + r) * L_SEQ + l0 + c;
  reinterpret_cast<u32x4*>(od)[0] = o0.u;
  reinterpret_cast<u32x4*>(od)[1] = o1.u;
}

// ---------- flash attention (causal, GQA) ----------
// block = 4 waves; wave w owns 16 query rows of a 64-row Q tile for one head.
// KV tiles of 64. MFMA 16x16x32; C layout: col=lane&15, row=(lane>>4)*4+reg (m89).
__global__ __launch_bounds__(256)
void flash_attn(const bf16* __restrict__ Q, const bf16* __restrict__ Kg,
                const bf16* __restrict__ Vt, bf16* __restrict__ Og) {
  __shared__ bf16 Ks[64 * 68];       // K[j][d], pitch 68
  __shared__ bf16 Vs[64 * 68];       // V^T[d][j], pitch 68
  __shared__ bf16 Ps[4][16 * 68];    // per-wave P[q][j], pitch 68
  const int tid = threadIdx.x;
  const int w = tid >> 6, l = tid & 63;
  const int lq = l & 15, lg = l >> 4;
  const int h = blockIdx.x >> 5;
  const int qt = blockIdx.x & 31;
  const int kvh = h >> 2;
  const int q0 = qt * 64;

  // Q fragments in registers (A-frag: row = l&15, k = (l>>4)*8 + e)
  const bf16* qp = Q + (long)(q0 + w * 16 + lq) * DMODEL + h * HDIM + lg * 8;
  const bf16x8 qf0 = *reinterpret_cast<const bf16x8*>(qp);
  const bf16x8 qf1 = *reinterpret_cast<const bf16x8*>(qp + 32);

  f32x4 o[4];
  float m[4], ll[4];
#pragma unroll
  for (int i = 0; i < 4; ++i) { o[i] = f32x4{0.f, 0.f, 0.f, 0.f}; m[i] = -__builtin_inff(); ll[i] = 0.f; }

  const int srow = tid >> 2;                 // 0..63
  const int sc = (tid & 3) * 16;             // 16-elem chunk
  const bf16* kgbase = Kg + kvh * HDIM + sc;
  const bf16* vgbase = Vt + ((long)kvh * HDIM + srow) * L_SEQ + sc;

  for (int kt = 0; kt <= qt; ++kt) {
    const int k0 = kt * 64;
    {
      const u32x4* gk = reinterpret_cast<const u32x4*>(kgbase + (long)(k0 + srow) * (NKVH * HDIM));
      u32x4 a = gk[0], b = gk[1];
      bf16* dk = &Ks[srow * 68 + sc];
      reinterpret_cast<u32x2*>(dk)[0] = u32x2{a.x, a.y};
      reinterpret_cast<u32x2*>(dk)[1] = u32x2{a.z, a.w};
      reinterpret_cast<u32x2*>(dk)[2] = u32x2{b.x, b.y};
      reinterpret_cast<u32x2*>(dk)[3] = u32x2{b.z, b.w};
      const u32x4* gv = reinterpret_cast<const u32x4*>(vgbase + k0);
      u32x4 cvx = gv[0], dvx = gv[1];
      bf16* dv = &Vs[srow * 68 + sc];
      reinterpret_cast<u32x2*>(dv)[0] = u32x2{cvx.x, cvx.y};
      reinterpret_cast<u32x2*>(dv)[1] = u32x2{cvx.z, cvx.w};
      reinterpret_cast<u32x2*>(dv)[2] = u32x2{dvx.x, dvx.y};
      reinterpret_cast<u32x2*>(dv)[3] = u32x2{dvx.z, dvx.w};
    }
    __syncthreads();

    // S = Q * K^T  (B-frag from K rows: col=lane&15 -> key, k = d)
    f32x4 s[4];
#pragma unroll
    for (int ct = 0; ct < 4; ++ct) {
      s[ct] = f32x4{0.f, 0.f, 0.f, 0.f};
      const bf16* kp = &Ks[(ct * 16 + lq) * 68 + lg * 8];
      s[ct] = __builtin_amdgcn_mfma_f32_16x16x32_bf16(qf0, lds_ld8(kp), s[ct], 0, 0, 0);
      s[ct] = __builtin_amdgcn_mfma_f32_16x16x32_bf16(qf1, lds_ld8(kp + 32), s[ct], 0, 0, 0);
    }

    if (kt == qt) {   // diagonal tile: causal mask
#pragma unroll
      for (int ct = 0; ct < 4; ++ct) {
        const int j = k0 + ct * 16 + lq;
#pragma unroll
        for (int r = 0; r < 4; ++r) {
          const int i = q0 + w * 16 + lg * 4 + r;
          if (j > i) s[ct][r] = -__builtin_inff();
        }
      }
    }

    // online softmax (row = lg*4+r, 16 cols per ct spread over 16-lane group)
    float al[4];
#pragma unroll
    for (int r = 0; r < 4; ++r) {
      float v = fmaxf(fmaxf(s[0][r], s[1][r]), fmaxf(s[2][r], s[3][r]));
      v = fmaxf(v, __shfl_xor(v, 1));
      v = fmaxf(v, __shfl_xor(v, 2));
      v = fmaxf(v, __shfl_xor(v, 4));
      v = fmaxf(v, __shfl_xor(v, 8));
      const float mn = fmaxf(m[r], v);
      al[r] = expf(m[r] - mn);
      m[r] = mn;
    }
#pragma unroll
    for (int ct = 0; ct < 4; ++ct)
#pragma unroll
      for (int r = 0; r < 4; ++r) s[ct][r] = expf(s[ct][r] - m[r]);
#pragma unroll
    for (int r = 0; r < 4; ++r) {
      float rs = s[0][r] + s[1][r] + s[2][r] + s[3][r];
      rs += __shfl_xor(rs, 1);
      rs += __shfl_xor(rs, 2);
      rs += __shfl_xor(rs, 4);
      rs += __shfl_xor(rs, 8);
      ll[r] = ll[r] * al[r] + rs;
      o[0][r] *= al[r]; o[1][r] *= al[r]; o[2][r] *= al[r]; o[3][r] *= al[r];
    }
    // write P (bf16) to per-wave LDS for layout transpose
#pragma unroll
    for (int ct = 0; ct < 4; ++ct)
#pragma unroll
      for (int r = 0; r < 4; ++r)
        Ps[w][(lg * 4 + r) * 68 + ct * 16 + lq] = (bf16)s[ct][r];
    __syncthreads();

    // O += P * V   (A-frag from P rows; B-frag from V^T rows: col=lane&15 -> d)
    const bf16* pp = &Ps[w][lq * 68 + lg * 8];
    const bf16x8 pa0 = lds_ld8(pp);
    const bf16x8 pa1 = lds_ld8(pp + 32);
#pragma unroll
    for (int dt = 0; dt < 4; ++dt) {
      const bf16* vp = &Vs[(dt * 16 + lq) * 68 + lg * 8];
      o[dt] = __builtin_amdgcn_mfma_f32_16x16x32_bf16(pa0, lds_ld8(vp), o[dt], 0, 0, 0);
      o[dt] = __builtin_amdgcn_mfma_f32_16x16x32_bf16(pa1, lds_ld8(vp + 32), o[dt], 0, 0, 0);
    }
    __syncthreads();
  }

#pragma unroll
  for (int dt = 0; dt < 4; ++dt)
#pragma unroll
    for (int r = 0; r < 4; ++r) {
      const long i = q0 + w * 16 + lg * 4 + r;
      Og[i * (long)DMODEL + h * HDIM + dt * 16 + lq] = (bf16)(o[dt][r] / ll[r]);
    }
}

// ---------- launch ----------
extern "C" void kernel_launch(void* const* d_in, const int* in_sizes, int n_in,
                              void* d_out, int out_size, void* d_ws, size_t ws_size,
                              hipStream_t stream) {
  const float* x       = (const float*)d_in[0];
  const float* w_qkv   = (const float*)d_in[1];
  const float* w_out   = (const float*)d_in[2];
  const float* q_gamma = (const float*)d_in[3];
  const float* k_gamma = (const float*)d_in[4];
  // d_in[5] = mask (causal tril) — implemented analytically.

  char* ws = (char*)d_ws;
  bf16* xb  = (bf16*)(ws);                       //  8 MiB  x bf16
  bf16* wqb = (bf16*)(ws + (8ul  << 20));        // 12 MiB  w_qkv bf16
  bf16* wob = (bf16*)(ws + (20ul << 20));        //  8 MiB  w_out bf16
  bf16* qkv = (bf16*)(ws + (28ul << 20));        // 12 MiB  qkv bf16
  bf16* qb  = (bf16*)(ws + (40ul << 20));        //  8 MiB  roped/normed Q (pre-scaled)
  bf16* kb  = (bf16*)(ws + (48ul << 20));        //  2 MiB  roped/normed K
  bf16* vt  = (bf16*)(ws + (50ul << 20));        //  2 MiB  V^T
  bf16* ao  = (bf16*)(ws + (52ul << 20));        //  8 MiB  attention out
  float* out = (float*)d_out;

  cvt_f32_bf16<<<2048, 256, 0, stream>>>(x, xb, (long)L_SEQ * DMODEL);
  cvt_f32_bf16<<<2048, 256, 0, stream>>>(w_qkv, wqb, (long)QKV_N * DMODEL);
  cvt_f32_bf16<<<2048, 256, 0, stream>>>(w_out, wob, (long)DMODEL * DMODEL);

  gemm_bt<bf16><<<dim3(QKV_N / 128, L_SEQ / 128), 256, 0, stream>>>(xb, wqb, qkv, L_SEQ, QKV_N, DMODEL);

  rope_rms<<<(L_SEQ * 40) / 4, 256, 0, stream>>>(qkv, q_gamma, k_gamma, qb, kb);
  vtrans<<<NKVH * (L_SEQ / 64), 256, 0, stream>>>(qkv, vt);

  flash_attn<<<NQH * (L_SEQ / 64), 256, 0, stream>>>(qb, kb, vt, ao);

  gemm_bt<float><<<dim3(DMODEL / 128, L_SEQ / 128), 256, 0, stream>>>(ao, wob, out, L_SEQ, DMODEL, DMODEL);
}

// Round 2
// 222.299 us; speedup vs baseline: 1.4504x; 1.4504x over previous
//
#include <hip/hip_runtime.h>

using bf16   = __bf16;
using bf16x4 = __bf16 __attribute__((ext_vector_type(4)));
using bf16x8 = __bf16 __attribute__((ext_vector_type(8)));
using f32x4  = float __attribute__((ext_vector_type(4)));
using f32x16 = float __attribute__((ext_vector_type(16)));
using u32x2  = unsigned int __attribute__((ext_vector_type(2)));
using u32x4  = unsigned int __attribute__((ext_vector_type(4)));

#define L_SEQ  2048
#define DMODEL 2048
#define NQH    32
#define NKVH   8
#define HDIM   64
#define QKV_N  3072   // NQH*HDIM + 2*NKVH*HDIM

// ---------- helpers ----------
__device__ __forceinline__ void gload_lds16(const void* g, void* lds) {
  __builtin_amdgcn_global_load_lds((__attribute__((address_space(1))) void*)(g),
                                   (__attribute__((address_space(3))) void*)(lds),
                                   16, 0, 0);
}

__device__ __forceinline__ unsigned pack2(float a, float b) {
  union { bf16 h[2]; unsigned u; } x;
  x.h[0] = (bf16)a; x.h[1] = (bf16)b;
  return x.u;
}

// ---------- fp32 -> bf16 convert ----------
__global__ void cvt_f32_bf16(const float* __restrict__ in, bf16* __restrict__ out, long n) {
  const long stride = (long)gridDim.x * blockDim.x;
  const long n4 = n >> 2;
  for (long i = (long)blockIdx.x * blockDim.x + threadIdx.x; i < n4; i += stride) {
    const float4 v = reinterpret_cast<const float4*>(in)[i];
    bf16x4 o = { (bf16)v.x, (bf16)v.y, (bf16)v.z, (bf16)v.w };
    reinterpret_cast<bf16x4*>(out)[i] = o;
  }
}

// ---------- bf16 GEMM: C(MxN) = A(MxK) * B(NxK)^T, 128x128 tile, BK=64 ----------
template <typename OutT>
__global__ __launch_bounds__(256)
void gemm_bt(const bf16* __restrict__ A, const bf16* __restrict__ B,
             OutT* __restrict__ C, int M, int N, int K) {
  __shared__ bf16 As[128 * 64];
  __shared__ bf16 Bs[128 * 64];
  const int tid = threadIdx.x;
  const int w = tid >> 6, l = tid & 63;
  const int wr = w >> 1, wc = w & 1;
  const int lq = l & 15, lg = l >> 4;
  const long m0 = (long)blockIdx.y * 128;
  const long n0 = (long)blockIdx.x * 128;

  const int lrow = l >> 3;
  const int scol = ((l & 7) ^ lrow) << 3;   // swizzled element column within BK

  f32x4 acc[4][4];
#pragma unroll
  for (int i = 0; i < 4; ++i)
#pragma unroll
    for (int j = 0; j < 4; ++j) acc[i][j] = f32x4{0.f, 0.f, 0.f, 0.f};

  for (int k0 = 0; k0 < K; k0 += 64) {
#pragma unroll
    for (int i = 0; i < 4; ++i) {
      const int r0 = (w * 4 + i) * 8;
      gload_lds16(A + (m0 + r0 + lrow) * (long)K + k0 + scol, &As[r0 * 64]);
      gload_lds16(B + (n0 + r0 + lrow) * (long)K + k0 + scol, &Bs[r0 * 64]);
    }
    __syncthreads();
#pragma unroll
    for (int kk = 0; kk < 2; ++kk) {
      bf16x8 af[4], bfr[4];
#pragma unroll
      for (int t = 0; t < 4; ++t) {
        const int rowA = wr * 64 + t * 16 + lq;
        const int blkA = (kk * 4 + lg) ^ (rowA & 7);
        af[t] = *reinterpret_cast<const bf16x8*>(&As[rowA * 64 + blkA * 8]);
        const int rowB = wc * 64 + t * 16 + lq;
        const int blkB = (kk * 4 + lg) ^ (rowB & 7);
        bfr[t] = *reinterpret_cast<const bf16x8*>(&Bs[rowB * 64 + blkB * 8]);
      }
#pragma unroll
      for (int mt = 0; mt < 4; ++mt)
#pragma unroll
        for (int nt = 0; nt < 4; ++nt)
          acc[mt][nt] = __builtin_amdgcn_mfma_f32_16x16x32_bf16(af[mt], bfr[nt], acc[mt][nt], 0, 0, 0);
    }
    __syncthreads();
  }

#pragma unroll
  for (int mt = 0; mt < 4; ++mt)
#pragma unroll
    for (int r = 0; r < 4; ++r) {
      const long row = m0 + wr * 64 + mt * 16 + lg * 4 + r;
#pragma unroll
      for (int nt = 0; nt < 4; ++nt) {
        const long col = n0 + wc * 64 + nt * 16 + lq;
        C[row * (long)N + col] = (OutT)acc[mt][nt][r];
      }
    }
}

// ---------- RoPE + RMSNorm for Q and K ----------
// Q scaled by SCALE*log2(e) = 0.125*1.442695 so attention works in exp2 domain.
__global__ __launch_bounds__(256)
void rope_rms(const bf16* __restrict__ qkv, const float* __restrict__ qg,
              const float* __restrict__ kg, bf16* __restrict__ qo, bf16* __restrict__ ko) {
  const int gid = blockIdx.x * 4 + (threadIdx.x >> 6);
  const int lane = threadIdx.x & 63;
  const int pos = gid / 40;
  const int hh = gid % 40;            // 0..31 q heads, 32..39 k heads
  const bool isq = hh < 32;
  const int col = isq ? hh * HDIM : NQH * HDIM + (hh - 32) * HDIM;

  float x = (float)qkv[(long)pos * QKV_N + col + lane];
  float p = __shfl_xor(x, 1);
  const float fi = (float)(lane & ~1) * (1.0f / 64.0f);
  const float inv = powf(50000.0f, -fi);
  const float ang = (float)pos * inv;
  const float sn = sinf(ang), cs = cosf(ang);
  const float r = (lane & 1) ? (p * sn + x * cs) : (x * cs - p * sn);

  float ss = r * r;
#pragma unroll
  for (int off = 1; off < 64; off <<= 1) ss += __shfl_xor(ss, off);
  const float scl = rsqrtf(ss * (1.0f / 64.0f) + 1e-5f);
  const float g = isq ? qg[lane] : kg[lane];
  const float o = r * scl * g;

  if (isq) qo[(long)pos * DMODEL + hh * HDIM + lane] = (bf16)(o * 0.18033688011112042f);
  else     ko[(long)pos * (NKVH * HDIM) + (hh - 32) * HDIM + lane] = (bf16)o;
}

// ---------- V transpose: qkv cols [2560,3072) -> vt[h][d][l] ----------
__global__ __launch_bounds__(256)
void vtrans(const bf16* __restrict__ qkv, bf16* __restrict__ vt) {
  __shared__ bf16 t[64][72];
  const int hh = blockIdx.x >> 5;
  const int l0 = (blockIdx.x & 31) * 64;
  const int r = threadIdx.x >> 2;            // 0..63
  const int c = (threadIdx.x & 3) * 16;      // 0,16,32,48

  const bf16* g = qkv + (long)(l0 + r) * QKV_N + (NQH * HDIM + NKVH * HDIM) + hh * HDIM + c;
  u32x4 u0 = reinterpret_cast<const u32x4*>(g)[0];
  u32x4 u1 = reinterpret_cast<const u32x4*>(g)[1];
  bf16* dst = &t[r][c];
  reinterpret_cast<u32x2*>(dst)[0] = u32x2{u0.x, u0.y};
  reinterpret_cast<u32x2*>(dst)[1] = u32x2{u0.z, u0.w};
  reinterpret_cast<u32x2*>(dst)[2] = u32x2{u1.x, u1.y};
  reinterpret_cast<u32x2*>(dst)[3] = u32x2{u1.z, u1.w};
  __syncthreads();

  union { bf16 b[8]; u32x4 u; } o0, o1;
#pragma unroll
  for (int j = 0; j < 8; ++j) { o0.b[j] = t[c + j][r]; o1.b[j] = t[c + 8 + j][r]; }
  bf16* od = vt + ((long)hh * HDIM + r) * L_SEQ + l0 + c;
  reinterpret_cast<u32x4*>(od)[0] = o0.u;
  reinterpret_cast<u32x4*>(od)[1] = o1.u;
}

// ---------- flash attention (causal, GQA), wave-independent, no LDS ----------
// Per wave: 32 q-rows of one head. Swapped MFMAs keep q lane-local:
//   ST[k][q] = mfma_32x32x16(A=K, B=Q) accumulated over 4 d-chunks
//   OT[d][q] = mfma_32x32x16(A=V^T, B=Pfrag) per 16-k slice
// C layout (m74/m101): col=lane&31, row=(r&3)+8*(r>>2)+4*(lane>>5).
__global__ __launch_bounds__(256)
void flash_attn(const bf16* __restrict__ Q, const bf16* __restrict__ Kg,
                const bf16* __restrict__ Vt, bf16* __restrict__ Og) {
  const int w = threadIdx.x >> 6, l = threadIdx.x & 63;
  const int lane31 = l & 31, hi = l >> 5;
  const int wg = blockIdx.x * 4 + w;
  const int h = wg & 31;                 // 4 heads per block (uniform work)
  const int qi = 63 - (wg >> 5);         // heavy q-tiles dispatched first
  const int kvh = h >> 2;
  const int q0 = qi * 32;
  const int q_abs = q0 + lane31;

  // Q fragments (B-frag of ST): lane -> Q[q0+lane31][c*16 + hi*8 + e]
  const bf16* qrow = Q + (long)q_abs * DMODEL + h * HDIM + hi * 8;
  bf16x8 qf[4];
#pragma unroll
  for (int c = 0; c < 4; ++c) qf[c] = *reinterpret_cast<const bf16x8*>(qrow + c * 16);

  f32x16 o0, o1;
#pragma unroll
  for (int r = 0; r < 16; ++r) { o0[r] = 0.f; o1[r] = 0.f; }
  float m = -3.0e38f, lsum = 0.f;

  const bf16* kbase  = Kg + kvh * HDIM + hi * 8;
  const bf16* v0base = Vt + ((long)(kvh * HDIM + lane31)) * L_SEQ + hi * 8;

  const int nst = qi + 1;                // 32-key subtiles
  for (int sti = 0; sti < nst; ++sti) {
    const int kb0 = sti * 32;

    // ---- ST = K * Q^T over 4 d-chunks ----
    f32x16 st;
#pragma unroll
    for (int r = 0; r < 16; ++r) st[r] = 0.f;
#pragma unroll
    for (int c = 0; c < 4; ++c) {
      const bf16x8 kf = *reinterpret_cast<const bf16x8*>(
          kbase + (long)(kb0 + lane31) * (NKVH * HDIM) + c * 16);
      st = __builtin_amdgcn_mfma_f32_32x32x16_bf16(kf, qf[c], st, 0, 0, 0);
    }

    // ---- causal mask (diagonal region only) ----
    if (kb0 + 31 > q0) {
#pragma unroll
      for (int r = 0; r < 16; ++r) {
        const int k_abs = kb0 + (r & 3) + 8 * (r >> 2) + 4 * hi;
        if (k_abs > q_abs) st[r] = -3.0e38f;
      }
    }

    // ---- online softmax (base-2 domain; scale folded into Q) ----
    float mx = st[0];
#pragma unroll
    for (int r = 1; r < 16; ++r) mx = fmaxf(mx, st[r]);
    mx = fmaxf(mx, __shfl_xor(mx, 32));
    if (!__all(mx - m <= 8.0f)) {        // defer-max, THR=8
      const float mn = fmaxf(m, mx);
      const float al = __builtin_amdgcn_exp2f(m - mn);
      m = mn; lsum *= al;
#pragma unroll
      for (int r = 0; r < 16; ++r) { o0[r] *= al; o1[r] *= al; }
    }
    float p[16];
    float rs = 0.f;
#pragma unroll
    for (int r = 0; r < 16; ++r) { p[r] = __builtin_amdgcn_exp2f(st[r] - m); rs += p[r]; }
    rs += __shfl_xor(rs, 32);
    lsum += rs;

    // ---- PV: per 16-k slice, assemble P frag in-register, 2 d-tiles ----
#pragma unroll
    for (int s = 0; s < 2; ++s) {
      const int j = s * 8;
      const unsigned W0 = pack2(p[j + 0], p[j + 1]);
      const unsigned W1 = pack2(p[j + 2], p[j + 3]);
      const unsigned W2 = pack2(p[j + 4], p[j + 5]);
      const unsigned W3 = pack2(p[j + 6], p[j + 7]);
      const unsigned X0 = (unsigned)__shfl_xor((int)W0, 32);
      const unsigned X1 = (unsigned)__shfl_xor((int)W1, 32);
      const unsigned X2 = (unsigned)__shfl_xor((int)W2, 32);
      const unsigned X3 = (unsigned)__shfl_xor((int)W3, 32);
      const u32x4 pw = { hi ? X2 : W0, hi ? X3 : W1, hi ? W2 : X0, hi ? W3 : X1 };
      const bf16x8 pf = __builtin_bit_cast(bf16x8, pw);
      const long kcol = kb0 + s * 16;
      const bf16x8 va = *reinterpret_cast<const bf16x8*>(v0base + kcol);
      const bf16x8 vb = *reinterpret_cast<const bf16x8*>(v0base + 32 * (long)L_SEQ + kcol);
      o0 = __builtin_amdgcn_mfma_f32_32x32x16_bf16(va, pf, o0, 0, 0, 0);
      o1 = __builtin_amdgcn_mfma_f32_32x32x16_bf16(vb, pf, o1, 0, 0, 0);
    }
  }

  // ---- normalize + store: lane owns q-row, regs span d ----
  const float rl = 1.0f / lsum;
  bf16* orow = Og + (long)q_abs * DMODEL + h * HDIM;
#pragma unroll
  for (int g = 0; g < 4; ++g) {
    const int d0 = 8 * g + 4 * hi;
    u32x2 s0 = { pack2(o0[4 * g + 0] * rl, o0[4 * g + 1] * rl),
                 pack2(o0[4 * g + 2] * rl, o0[4 * g + 3] * rl) };
    u32x2 s1 = { pack2(o1[4 * g + 0] * rl, o1[4 * g + 1] * rl),
                 pack2(o1[4 * g + 2] * rl, o1[4 * g + 3] * rl) };
    *reinterpret_cast<u32x2*>(orow + d0) = s0;
    *reinterpret_cast<u32x2*>(orow + 32 + d0) = s1;
  }
}

// ---------- launch ----------
extern "C" void kernel_launch(void* const* d_in, const int* in_sizes, int n_in,
                              void* d_out, int out_size, void* d_ws, size_t ws_size,
                              hipStream_t stream) {
  const float* x       = (const float*)d_in[0];
  const float* w_qkv   = (const float*)d_in[1];
  const float* w_out   = (const float*)d_in[2];
  const float* q_gamma = (const float*)d_in[3];
  const float* k_gamma = (const float*)d_in[4];
  // d_in[5] = mask (causal tril) — implemented analytically.

  char* ws = (char*)d_ws;
  bf16* xb  = (bf16*)(ws);                       //  8 MiB  x bf16
  bf16* wqb = (bf16*)(ws + (8ul  << 20));        // 12 MiB  w_qkv bf16
  bf16* wob = (bf16*)(ws + (20ul << 20));        //  8 MiB  w_out bf16
  bf16* qkv = (bf16*)(ws + (28ul << 20));        // 12 MiB  qkv bf16
  bf16* qb  = (bf16*)(ws + (40ul << 20));        //  8 MiB  roped/normed Q (pre-scaled)
  bf16* kb  = (bf16*)(ws + (48ul << 20));        //  2 MiB  roped/normed K
  bf16* vt  = (bf16*)(ws + (50ul << 20));        //  2 MiB  V^T
  bf16* ao  = (bf16*)(ws + (52ul << 20));        //  8 MiB  attention out
  float* out = (float*)d_out;

  cvt_f32_bf16<<<2048, 256, 0, stream>>>(x, xb, (long)L_SEQ * DMODEL);
  cvt_f32_bf16<<<2048, 256, 0, stream>>>(w_qkv, wqb, (long)QKV_N * DMODEL);
  cvt_f32_bf16<<<2048, 256, 0, stream>>>(w_out, wob, (long)DMODEL * DMODEL);

  gemm_bt<bf16><<<dim3(QKV_N / 128, L_SEQ / 128), 256, 0, stream>>>(xb, wqb, qkv, L_SEQ, QKV_N, DMODEL);

  rope_rms<<<(L_SEQ * 40) / 4, 256, 0, stream>>>(qkv, q_gamma, k_gamma, qb, kb);
  vtrans<<<NKVH * (L_SEQ / 64), 256, 0, stream>>>(qkv, vt);

  flash_attn<<<(NQH * (L_SEQ / 32)) / 4, 256, 0, stream>>>(qb, kb, vt, ao);

  gemm_bt<float><<<dim3(DMODEL / 128, L_SEQ / 128), 256, 0, stream>>>(ao, wob, out, L_SEQ, DMODEL, DMODEL);
}